// Round 7
// baseline (432.086 us; speedup 1.0000x reference)
//
#include <hip/hip_runtime.h>
#include <hip/hip_bf16.h>
#include <math.h>

// Problem constants (match reference)
#define HEADS 8
#define HC 256            // HEADS*CHAN = D
#define NEG_SLOPE 0.2f    // leaky(t) = 0.6*t + 0.4*|t|

typedef __attribute__((ext_vector_type(8))) short short8;
typedef __attribute__((ext_vector_type(16))) float floatx16;

__device__ inline ushort bf16_rne(float f) {
    unsigned u = __float_as_uint(f);
    return (ushort)((u + 0x7FFFu + ((u >> 16) & 1u)) >> 16);
}
__device__ inline float bf2f(ushort u) {
    return __uint_as_float(((unsigned)u) << 16);
}

// ---------------------------------------------------------------------------
// Fused prep: [0, gcvt) blocks convert x -> xb (bf16, XOR-swizzled);
// [gcvt, gcvt+1024) blocks transpose W1/W2 -> wt1/wt2 (bf16, swizzled).
// Swizzle: 16B block j of row r stored at position j ^ (r&7), so the GEMM
// DMA stages rows verbatim and fragment ds_read_b128s hit all 8 bank-groups.
__global__ __launch_bounds__(256) void prep(
        const float* __restrict__ x, ushort* __restrict__ xb, long long nblk,
        int gcvt,
        const float* __restrict__ Wl1, const float* __restrict__ Wr1,
        ushort* __restrict__ wt1,
        const float* __restrict__ Wl2, const float* __restrict__ Wr2,
        ushort* __restrict__ wt2) {
    int bid = blockIdx.x;
    int t = threadIdx.x;
    if (bid < gcvt) {
        long long id = (long long)bid * 256 + t;
        if (id >= nblk) return;
        long long r = id >> 5;
        int j = (int)(id & 31);
        const float4* p = (const float4*)(x + id * 8);
        float4 a = p[0], b = p[1];
        short8 pk;
        pk[0] = (short)bf16_rne(a.x); pk[1] = (short)bf16_rne(a.y);
        pk[2] = (short)bf16_rne(a.z); pk[3] = (short)bf16_rne(a.w);
        pk[4] = (short)bf16_rne(b.x); pk[5] = (short)bf16_rne(b.y);
        pk[6] = (short)bf16_rne(b.z); pk[7] = (short)bf16_rne(b.w);
        int jx = j ^ ((int)r & 7);
        *(short8*)(xb + r * 256 + jx * 8) = pk;
    } else {
        int w = bid - gcvt;            // 0..1023
        int n = w & 511;               // output col 0..511
        int k = t;                     // 0..255
        const float* W;
        ushort* wt;
        if (w < 512) { W = (n < 256) ? Wl1 : Wr1; wt = wt1; }
        else         { W = (n < 256) ? Wl2 : Wr2; wt = wt2; }
        int col = n & 255;
        int jx = (k >> 3) ^ (n & 7);
        wt[n * HC + jx * 8 + (k & 7)] = bf16_rne(W[k * HC + col]);
    }
}

// ---------------------------------------------------------------------------
// MFMA dual-GEMM: C[N,512] = A[N,256](bf16,swz) x wt(bf16,swz), bf16 out.
// 64x64 C-tile, K=256 fully staged via global_load_lds width-16 DMA.
// OPERAND-SWAPPED mfma: wt fragments feed the A-slot, x fragments the
// B-slot (per-lane LDS reads identical for both slots), so the D layout
// (col=lane&31, row=reg-based) gives each lane ONE x-row and 16 output
// cols in 4 runs of 4 -> epilogue = 4 ushort4 stores under one m<N guard.
__global__ __launch_bounds__(256) void gemm_mfma(
        const ushort* __restrict__ A, const ushort* __restrict__ wt,
        ushort* __restrict__ xl, ushort* __restrict__ xr, int N) {
    __shared__ ushort lA[64 * 256];
    __shared__ ushort lB[64 * 256];
    int local = blockIdx.x & 127;
    int grp   = blockIdx.x >> 7;
    int mt = grp * 16 + (local & 15);   // same XCD for all nt of this mt
    int nt = local >> 4;
    int m0 = mt * 64, n0 = nt * 64;
    int t = threadIdx.x;
    int lane = t & 63, wv = t >> 6;

    // ---- DMA staging: each wave copies 8x 1KB chunks of A and of B ----
    {
        const ushort* gA = A + (long long)m0 * HC;   // rows contiguous (swz)
        const ushort* gB = wt + (long long)n0 * HC;
        #pragma unroll
        for (int i = 0; i < 8; ++i) {
            int off = (wv * 8 + i) * 512;            // ushorts (1 KB chunks)
            __builtin_amdgcn_global_load_lds(
                (const __attribute__((address_space(1))) unsigned int*)(gA + off + lane * 8),
                (__attribute__((address_space(3))) unsigned int*)(lA + off), 16, 0, 0);
            __builtin_amdgcn_global_load_lds(
                (const __attribute__((address_space(1))) unsigned int*)(gB + off + lane * 8),
                (__attribute__((address_space(3))) unsigned int*)(lB + off), 16, 0, 0);
        }
    }
    __syncthreads();

    // ---- k-loop: wave quadrant x-rows (wv&1)*32, wt-rows (wv>>1)*32 ----
    int rA = (wv & 1) * 32 + (lane & 31);
    int rB = (wv >> 1) * 32 + (lane & 31);
    int kh = lane >> 5;                // k-half of the fragment
    int sA = rA & 7, sB = rB & 7;
    floatx16 acc;
    #pragma unroll
    for (int i = 0; i < 16; ++i) acc[i] = 0.f;
    #pragma unroll
    for (int step = 0; step < 16; ++step) {
        int j = step * 2 + kh;
        short8 a = *(const short8*)&lA[rA * 256 + ((j ^ sA) * 8)];
        short8 b = *(const short8*)&lB[rB * 256 + ((j ^ sB) * 8)];
        // operand swap: wt -> A-slot, x -> B-slot  => D[n][m] orientation
        acc = __builtin_amdgcn_mfma_f32_32x32x16_bf16(b, a, acc, 0, 0, 0);
    }

    // ---- epilogue: lane owns x-row m = m0+rA; regs span n in 4 runs of 4:
    //      n = n0 + (wv>>1)*32 + 4*kh + 8*g + (reg&3)
    int m = m0 + rA;
    if (m < N) {
        ushort* obase = (nt < 4) ? xl : xr;          // xl/xr are PLAIN layout
        ushort* po = obase + (long long)m * HC +
                     (n0 & 255) + (wv >> 1) * 32 + 4 * kh;
        #pragma unroll
        for (int g = 0; g < 4; ++g) {
            ushort4 pk;
            pk.x = bf16_rne(acc[g * 4 + 0]);
            pk.y = bf16_rne(acc[g * 4 + 1]);
            pk.z = bf16_rne(acc[g * 4 + 2]);
            pk.w = bf16_rne(acc[g * 4 + 3]);
            *(ushort4*)(po + 8 * g) = pk;
        }
    }
}

// ---------------------------------------------------------------------------
// Histogram of dst (self-loops appended implicitly: edge w>=E is node w-E)
__global__ void hist_dst(const int* __restrict__ eidx, int E, int N,
                         int* __restrict__ counts) {
    int w = blockIdx.x * blockDim.x + threadIdx.x;
    int Etot = E + N;
    if (w >= Etot) return;
    int d = (w < E) ? eidx[E + w] : (w - E);
    atomicAdd(&counts[d], 1);
}

// ---------------------------------------------------------------------------
// 3-kernel exclusive scan: per-block scan -> block-sum scan -> add offsets
__global__ __launch_bounds__(1024) void scan_local(
        const int* __restrict__ counts, int* __restrict__ rowptr,
        int* __restrict__ bsum, int N) {
    __shared__ int wsums[16];
    int t = threadIdx.x, lane = t & 63, wv = t >> 6;
    int i = blockIdx.x * 1024 + t;
    int v = (i < N) ? counts[i] : 0;
    int orig = v;
    #pragma unroll
    for (int off = 1; off < 64; off <<= 1) {
        int n = __shfl_up(v, off, 64);
        if (lane >= off) v += n;
    }
    if (lane == 63) wsums[wv] = v;
    __syncthreads();
    int woff = 0, total = 0;
    #pragma unroll
    for (int w_ = 0; w_ < 16; ++w_) {
        int s = wsums[w_];
        if (w_ < wv) woff += s;
        total += s;
    }
    if (i < N) rowptr[i] = v + woff - orig;
    if (t == 0) bsum[blockIdx.x] = total;
}

__global__ void scan_bsums(const int* __restrict__ bsum, int* __restrict__ bsum2,
                           int* __restrict__ rowptr, int nb, int N) {
    int lane = threadIdx.x;   // 64 threads, nb <= 64
    int v = (lane < nb) ? bsum[lane] : 0;
    int orig = v;
    #pragma unroll
    for (int off = 1; off < 64; off <<= 1) {
        int n = __shfl_up(v, off, 64);
        if (lane >= off) v += n;
    }
    if (lane < nb) bsum2[lane] = v - orig;
    if (lane == 63) rowptr[N] = v;
}

__global__ __launch_bounds__(1024) void scan_add(
        int* __restrict__ rowptr, const int* __restrict__ bsum2, int N) {
    int i = blockIdx.x * 1024 + threadIdx.x;
    if (i < N) rowptr[i] += bsum2[blockIdx.x];
}

// ---------------------------------------------------------------------------
__global__ void scatter_edges(const int* __restrict__ eidx, int E, int N,
                              const int* __restrict__ rowptr,
                              int* __restrict__ fill, int* __restrict__ srcS) {
    int w = blockIdx.x * blockDim.x + threadIdx.x;
    int Etot = E + N;
    if (w >= Etot) return;
    int s, d;
    if (w < E) { s = eidx[w]; d = eidx[E + w]; }
    else       { s = w - E;   d = w - E; }
    int pos = rowptr[d] + atomicAdd(&fill[d], 1);
    srcS[pos] = s;
}

// ---------------------------------------------------------------------------
// Fused GATv2 per-node: one wave per dst node (lane owns 4 channels,
// head = lane>>3, unroll-2 with independent accumulators). LeakyReLU folded
// as 0.6*t + 0.4*|t| (abs is a free VALU input modifier). No atomics.
// LAYER1: ELU + bf16 SWIZZLED store (feeds layer-2 GEMM DMA); else fp32.
template <int LAYER1>
__global__ __launch_bounds__(256) void gat_node(
        const ushort* __restrict__ xl, const ushort* __restrict__ xr,
        const float* __restrict__ att, const float* __restrict__ bias,
        const int* __restrict__ rowptr, const int* __restrict__ srcS,
        void* __restrict__ outp, int N) {
    int node = blockIdx.x * 4 + (threadIdx.x >> 6);
    int lane = threadIdx.x & 63;
    if (node >= N) return;
    int beg = rowptr[node], end = rowptr[node + 1];

    ushort4 xu = *(const ushort4*)(xr + (long long)node * HC + lane * 4);
    float xr0 = bf2f(xu.x), xr1 = bf2f(xu.y), xr2 = bf2f(xu.z), xr3 = bf2f(xu.w);
    float4 atv = *(const float4*)(att + lane * 4);

    float ssA = 0.f, ssB = 0.f;
    float4 aA = make_float4(0.f, 0.f, 0.f, 0.f);
    float4 aB = make_float4(0.f, 0.f, 0.f, 0.f);

#define EDGE_BODY(P, SS, AC)                                                   \
    {                                                                          \
        int s = srcS[P];                                                       \
        ushort4 u = *(const ushort4*)(xl + (long long)s * HC + lane * 4);      \
        float v0 = bf2f(u.x), v1 = bf2f(u.y), v2 = bf2f(u.z), v3 = bf2f(u.w);  \
        float t0 = v0 + xr0, t1 = v1 + xr1, t2 = v2 + xr2, t3 = v3 + xr3;      \
        float st = atv.x * t0;                                                 \
        st = fmaf(atv.y, t1, st);                                              \
        st = fmaf(atv.z, t2, st);                                              \
        st = fmaf(atv.w, t3, st);                                              \
        float sa = atv.x * fabsf(t0);                                          \
        sa = fmaf(atv.y, fabsf(t1), sa);                                       \
        sa = fmaf(atv.z, fabsf(t2), sa);                                       \
        sa = fmaf(atv.w, fabsf(t3), sa);                                       \
        float sc = fmaf(0.6f, st, 0.4f * sa);                                  \
        sc += __shfl_xor(sc, 1, 64);                                           \
        sc += __shfl_xor(sc, 2, 64);                                           \
        sc += __shfl_xor(sc, 4, 64);                                           \
        float ex = __expf(sc);                                                 \
        SS += ex;                                                              \
        AC.x = fmaf(ex, v0, AC.x); AC.y = fmaf(ex, v1, AC.y);                  \
        AC.z = fmaf(ex, v2, AC.z); AC.w = fmaf(ex, v3, AC.w);                  \
    }

    int p = beg;
    for (; p + 1 < end; p += 2) {
        EDGE_BODY(p, ssA, aA)
        EDGE_BODY(p + 1, ssB, aB)
    }
    if (p < end) EDGE_BODY(p, ssA, aA)
#undef EDGE_BODY

    float inv = 1.f / (ssA + ssB);
    float4 bv = *(const float4*)(bias + lane * 4);
    float o0 = (aA.x + aB.x) * inv + bv.x;
    float o1 = (aA.y + aB.y) * inv + bv.y;
    float o2 = (aA.z + aB.z) * inv + bv.z;
    float o3 = (aA.w + aB.w) * inv + bv.w;
    if (LAYER1) {
        o0 = o0 > 0.f ? o0 : expm1f(o0);
        o1 = o1 > 0.f ? o1 : expm1f(o1);
        o2 = o2 > 0.f ? o2 : expm1f(o2);
        o3 = o3 > 0.f ? o3 : expm1f(o3);
        ushort4 pk;
        pk.x = bf16_rne(o0); pk.y = bf16_rne(o1);
        pk.z = bf16_rne(o2); pk.w = bf16_rne(o3);
        // swizzled store: 16B block j = lane>>1 -> position j ^ (node&7)
        int jx = (lane >> 1) ^ (node & 7);
        *(ushort4*)((ushort*)outp + (long long)node * HC + jx * 8 +
                    (lane & 1) * 4) = pk;
    } else {
        *(float4*)((float*)outp + (long long)node * HC + lane * 4) =
            make_float4(o0, o1, o2, o3);
    }
}

// ---------------------------------------------------------------------------
extern "C" void kernel_launch(void* const* d_in, const int* in_sizes, int n_in,
                              void* d_out, int out_size, void* d_ws, size_t ws_size,
                              hipStream_t stream) {
    const float* x    = (const float*)d_in[0];
    const int*   eidx = (const int*)d_in[1];
    const float* Wl1  = (const float*)d_in[2];
    const float* Wr1  = (const float*)d_in[3];
    const float* att1 = (const float*)d_in[4];
    const float* b1   = (const float*)d_in[5];
    const float* Wl2  = (const float*)d_in[6];
    const float* Wr2  = (const float*)d_in[7];
    const float* att2 = (const float*)d_in[8];
    const float* b2   = (const float*)d_in[9];
    float* out = (float*)d_out;

    const int N = in_sizes[0] / HC;       // 50000
    const int E = in_sizes[1] / 2;        // 800000
    const int Etot = E + N;
    const long long NHC = (long long)N * HC;

    // workspace layout (16B-aligned bf16 region first)
    ushort* xl   = (ushort*)d_ws;         // N*HC bf16 (plain)
    ushort* xr   = xl + NHC;              // N*HC     (plain)
    ushort* hbuf = xr + NHC;              // N*HC     (swizzled)
    ushort* xb   = hbuf + NHC;            // N*HC     (swizzled)
    ushort* wt1  = xb + NHC;              // 512*HC   (swizzled)
    ushort* wt2  = wt1 + 512 * HC;        // 512*HC   (swizzled)
    int* rowptr  = (int*)(wt2 + 512 * HC);// N+1
    int* counts  = rowptr + (N + 1);      // N
    int* fill    = counts + N;            // N (contiguous with counts)
    int* bsum    = fill + N;              // 64
    int* bsum2   = bsum + 64;             // 64
    int* srcS    = bsum2 + 64;            // Etot

    const int TB = 256;
    dim3 blk(TB);
    int gEdgesT = (Etot + TB - 1) / TB;
    int mtTiles = (N + 63) / 64;                  // 782
    int gGemm   = ((mtTiles + 15) / 16) * 128;    // supergrouped (16 mt x 8 nt)
    int gNode   = (N + 3) / 4;
    int nb      = (N + 1023) / 1024;      // 49 <= 64
    long long nblk = NHC / 8;
    int gCvt    = (int)((nblk + TB - 1) / TB);

    // ---- fused prep (cvt + both weight transposes) + CSR build ----
    prep<<<gCvt + 1024, blk, 0, stream>>>(x, xb, nblk, gCvt,
                                          Wl1, Wr1, wt1, Wl2, Wr2, wt2);
    hipMemsetAsync(counts, 0, (size_t)2 * N * sizeof(int), stream);
    hist_dst<<<gEdgesT, blk, 0, stream>>>(eidx, E, N, counts);
    scan_local<<<nb, 1024, 0, stream>>>(counts, rowptr, bsum, N);
    scan_bsums<<<1, 64, 0, stream>>>(bsum, bsum2, rowptr, nb, N);
    scan_add<<<nb, 1024, 0, stream>>>(rowptr, bsum2, N);
    scatter_edges<<<gEdgesT, blk, 0, stream>>>(eidx, E, N, rowptr, fill, srcS);

    // ================= layer 1 =================
    gemm_mfma<<<gGemm, blk, 0, stream>>>(xb, wt1, xl, xr, N);
    gat_node<1><<<gNode, blk, 0, stream>>>(xl, xr, att1, b1, rowptr, srcS, hbuf, N);

    // ================= layer 2 =================
    gemm_mfma<<<gGemm, blk, 0, stream>>>(hbuf, wt2, xl, xr, N);
    gat_node<0><<<gNode, blk, 0, stream>>>(xl, xr, att2, b2, rowptr, srcS, out, N);
}